// Round 5
// baseline (766.988 us; speedup 1.0000x reference)
//
#include <hip/hip_runtime.h>
#include <hip/hip_bf16.h>
#include <stdint.h>

// Problem constants
#define L3D 3
#define BD 2
#define CD 2048
#define HW 3600
#define CH 256
#define HWP 3712   // 29 * 128, padded hw
#define KD 6144    // L3D * CD  (bytes per row in fp8 An/Bn)
#define SP 3712    // padded support dim
#define SP2 3840   // partial-ssq q stride
#define LB6 6      // L3D*BD
#define NPLANE 12  // both inputs' (l,b) planes
#define NT 48      // K-tiles in main GEMM: KD / 128
#define PVNT 58    // K-steps in PV GEMM: SP / 64

typedef __attribute__((ext_vector_type(8))) short short8;
typedef __attribute__((ext_vector_type(4))) float f32x4;
typedef __attribute__((ext_vector_type(4))) int i32x4;
typedef __attribute__((ext_vector_type(8))) int i32x8;

__device__ __forceinline__ short f2bf(float v) {
  uint32_t x = __float_as_uint(v);
  uint32_t r = (x + 0x7FFFu + ((x >> 16) & 1u)) >> 16;   // RNE
  return (short)(r & 0xFFFFu);
}

__device__ __forceinline__ float bf2f(short s) {
  return __uint_as_float(((uint32_t)(uint16_t)s) << 16);
}

__device__ __forceinline__ void load_lds16(const void* g, void* l) {
  __builtin_amdgcn_global_load_lds(
      (const __attribute__((address_space(1))) void*)g,
      (__attribute__((address_space(3))) void*)l, 16, 0, 0);
}

// ---------------- norm_k: sum-of-squares partials ----------------
__global__ __launch_bounds__(256) void norm_k(const float* __restrict__ fq,
                                              const float* __restrict__ fs,
                                              float* __restrict__ part) {
  const int qt = blockIdx.x * 256;
  const int j = blockIdx.y;
  const int cs = blockIdx.z;
  const bool isq = (j < LB6);
  const int lb = isq ? j : j - LB6;
  const float* x = (isq ? fq : fs) + (size_t)lb * CD * HW;

  const int tid = threadIdx.x;
  const int qg = tid & 63;
  const int cp = tid >> 6;          // 0..3
  const int q4 = qt + qg * 4;

  f32x4 a0 = (f32x4){0.f, 0.f, 0.f, 0.f};
  f32x4 a1 = a0, a2 = a0, a3 = a0;
  if (q4 < HW) {                    // HW % 4 == 0: float4 fully valid or fully out
    const float* p = x + ((size_t)cs * 256 + cp) * HW + q4;
    for (int i = 0; i < 64; i += 4) {
      f32x4 v0 = *reinterpret_cast<const f32x4*>(p + (size_t)(i + 0) * 4 * HW);
      f32x4 v1 = *reinterpret_cast<const f32x4*>(p + (size_t)(i + 1) * 4 * HW);
      f32x4 v2 = *reinterpret_cast<const f32x4*>(p + (size_t)(i + 2) * 4 * HW);
      f32x4 v3 = *reinterpret_cast<const f32x4*>(p + (size_t)(i + 3) * 4 * HW);
      a0 += v0 * v0; a1 += v1 * v1; a2 += v2 * v2; a3 += v3 * v3;
    }
  }
  f32x4 a = (a0 + a1) + (a2 + a3);

  __shared__ float rb[4][256];
  *reinterpret_cast<f32x4*>(&rb[cp][qg * 4]) = a;
  __syncthreads();
  float s = rb[0][tid] + rb[1][tid] + rb[2][tid] + rb[3][tid];
  part[((size_t)cs * NPLANE + j) * SP2 + qt + tid] = s;
}

// ---------------- trans_k: normalize + transpose + fp8 pack ----------------
__global__ __launch_bounds__(256) void trans_k(const float* __restrict__ fq,
                                               const float* __restrict__ fs,
                                               const float* __restrict__ cw,
                                               const float* __restrict__ part,
                                               uint8_t* __restrict__ An,
                                               uint8_t* __restrict__ Bn) {
  const int j = blockIdx.y;
  const int qt = blockIdx.x * 64;
  const int cg = blockIdx.z;
  const bool isq = (j < LB6);
  const int lb = isq ? j : j - LB6;
  const int l = lb / BD, b = lb % BD;
  const float* x = (isq ? fq : fs) + (size_t)lb * CD * HW;
  uint8_t* dst = isq ? An : Bn;

  const int tid = threadIdx.x;

  __shared__ float ivs[64];
  if (tid < 64) {
    const int q = qt + tid;
    float s = 0.f;
#pragma unroll
    for (int cs = 0; cs < 8; cs++) s += part[((size_t)cs * NPLANE + j) * SP2 + q];
    const float scale = isq ? (cw[l] * 32.0f) : 32.0f;  // fp8 range scaling
    ivs[tid] = (1.f / fmaxf(sqrtf(s), 1e-12f)) * scale;
  }

  __shared__ float tile[64][65];
  const int tx = tid & 63, partid = tid >> 6;
  const int q = qt + tx;
  const int wx = tid & 7, wy = tid >> 3;

  for (int t = 0; t < 8; t++) {
    const int ct = cg * 8 + t;
    const float* px = x + (size_t)ct * 64 * HW;
    __syncthreads();
#pragma unroll
    for (int r = 0; r < 16; r++) {
      int cl = r * 4 + partid;
      tile[cl][tx] = (q < HW) ? px[(size_t)cl * HW + q] : 0.f;
    }
    __syncthreads();
#pragma unroll
    for (int it = 0; it < 2; it++) {
      int qrow = wy + it * 32;
      int qq = qt + qrow;
      if (qq < HW) {
        float iv = ivs[qrow];
        float v[8];
#pragma unroll
        for (int jj = 0; jj < 8; jj++) v[jj] = tile[wx * 8 + jj][qrow] * iv;
        int lo = 0, hi = 0;
        lo = __builtin_amdgcn_cvt_pk_fp8_f32(v[0], v[1], lo, false);
        lo = __builtin_amdgcn_cvt_pk_fp8_f32(v[2], v[3], lo, true);
        hi = __builtin_amdgcn_cvt_pk_fp8_f32(v[4], v[5], hi, false);
        hi = __builtin_amdgcn_cvt_pk_fp8_f32(v[6], v[7], hi, true);
        int2 pk = make_int2(lo, hi);
        *reinterpret_cast<int2*>(dst + ((size_t)b * HWP + qq) * KD +
                                 (size_t)l * CD + ct * 64 + wx * 8) = pk;
      }
    }
  }
}

// ---------------- Main GEMM: MX-fp8, 256x256 tile, BK=128, m201 4-phase ----------------
// C-quadrant phases, 8 MFMA each; staging spread 2 loads/phase in dependency order
// (B0,B1 / B2,B3 / A0,A2 / A1,A3 of tile t+1 -> nxt). Counted waits, NEVER 0 in
// steady state:
//   ph1-end: vmcnt(4)  (certify cur's A1,A3 [2 oldest]; leave 4 B(t+1) in flight)
//   ph3-end: vmcnt(2)  (certify B(t+1)+A0,A2(t+1); leave A1,A3(t+1) in flight)
// Each vmcnt precedes a barrier: a wave's count only certifies its OWN staged slice.
// Phase body: {ds_read batch || 2 staging issues; bar; lgkm(0); prio1; 8 MFMA; prio0; bar}.
// LDS layout: row = 128 B = 8 chunks of 16 B; chunk c of row r at slot (c+r)&7.
// Bijective XCD swizzle (450 blocks): m-major A-panel-sharing groups per XCD L2.
__global__ __launch_bounds__(512, 2) void gemm_main(const uint8_t* __restrict__ A,
                                                    const uint8_t* __restrict__ B,
                                                    __hip_bfloat16* __restrict__ C) {
  // --- bijective XCD swizzle: 450 = 8*56 + 2 -> chunks {57,57,56,56,56,56,56,56}
  const int orig = blockIdx.x;
  const int xcd = orig & 7, idx = orig >> 3;
  const int wg = (xcd < 2 ? xcd * 57 : 114 + (xcd - 2) * 56) + idx;
  const int bz = wg / 225;
  const int lin = wg % 225;
  const int m_t = lin / 15, n_t = lin % 15;   // m-major: 15 consecutive share A-panel
  const int m0 = m_t * 256, n0 = n_t * 256;
  const int tid = threadIdx.x;
  const int lane = tid & 63;
  const int wv = tid >> 6;               // 0..7 waves: 2 (m) x 4 (n)

  __shared__ uint8_t lA[2][256 * 128];   // 64 KB
  __shared__ uint8_t lB[2][256 * 128];   // 64 KB

  const uint8_t* gA = A + (size_t)bz * HWP * KD;
  const uint8_t* gB = B + (size_t)bz * HWP * KD;

  const int r_loc = tid >> 3;            // 0..63: row within a 64-row staging call
  const int slot = tid & 7;              // LDS slot within row
  const int csw = (slot - r_loc) & 7;    // global chunk this lane fetches
  const int wavebase = (tid & ~63) * 16; // wave-uniform LDS byte base

  const int wr = (wv >> 2) * 128;        // wave m offset: 0 / 128
  const int wc = (wv & 3) * 64;          // wave n offset: 0/64/128/192
  const int ml = lane & 15;
  const int kg = lane >> 4;              // k-group: 32 contiguous k bytes per lane

  f32x4 acc[8][4];
#pragma unroll
  for (int i = 0; i < 8; i++)
#pragma unroll
    for (int jj = 0; jj < 4; jj++) acc[i][jj] = (f32x4){0.f, 0.f, 0.f, 0.f};

  auto stA = [&](int t, int bufi, int i) {
    load_lds16(gA + (size_t)(m0 + i * 64 + r_loc) * KD + t * 128 + csw * 16,
               &lA[bufi][i * 8192 + wavebase]);
  };
  auto stB = [&](int t, int bufi, int i) {
    load_lds16(gB + (size_t)(n0 + i * 64 + r_loc) * KD + t * 128 + csw * 16,
               &lB[bufi][i * 8192 + wavebase]);
  };

  auto rdfrag = [&](const uint8_t* base, int row) -> i32x8 {
    const uint8_t* rp = base + (row << 7);
    i32x4 lo = *reinterpret_cast<const i32x4*>(rp + (((kg * 2)     + row) & 7) * 16);
    i32x4 hi = *reinterpret_cast<const i32x4*>(rp + (((kg * 2 + 1) + row) & 7) * 16);
    return __builtin_shufflevector(lo, hi, 0, 1, 2, 3, 4, 5, 6, 7);
  };

  // prologue: tile 0 staged in order B0..B3, A0, A2, A1, A3 -> vmcnt(2) leaves A1,A3
  stB(0, 0, 0); stB(0, 0, 1); stB(0, 0, 2); stB(0, 0, 3);
  stA(0, 0, 0); stA(0, 0, 2); stA(0, 0, 1); stA(0, 0, 3);
  asm volatile("s_waitcnt vmcnt(2)" ::: "memory");
  __builtin_amdgcn_s_barrier();

  for (int t = 0; t < NT; t++) {
    const int cur = t & 1;
    const int nxt = cur ^ 1;
    const uint8_t* pA = lA[cur];
    const uint8_t* pB = lB[cur];
    const bool s1 = (t + 1 < NT);
    i32x8 afl[4], afh[4], bfl[2], bfh[2];

    // ---- ph0: quadrant (m-lo, n-lo); stage B(t+1) 0,1 ----
#pragma unroll
    for (int x = 0; x < 4; x++) afl[x] = rdfrag(pA, wr + x * 16 + ml);
#pragma unroll
    for (int x = 0; x < 2; x++) bfl[x] = rdfrag(pB, wc + x * 16 + ml);
    if (s1) { stB(t + 1, nxt, 0); stB(t + 1, nxt, 1); }
    __builtin_amdgcn_s_barrier();
    asm volatile("s_waitcnt lgkmcnt(0)");
    __builtin_amdgcn_s_setprio(1);
#pragma unroll
    for (int mt = 0; mt < 4; mt++)
#pragma unroll
      for (int nt = 0; nt < 2; nt++)
        acc[mt][nt] = __builtin_amdgcn_mfma_scale_f32_16x16x128_f8f6f4(
            afl[mt], bfl[nt], acc[mt][nt], 0, 0, 0, 0x7F7F7F7F, 0, 0x7F7F7F7F);
    __builtin_amdgcn_s_setprio(0);
    __builtin_amdgcn_s_barrier();

    // ---- ph1: (m-lo, n-hi); stage B(t+1) 2,3; certify cur A1,A3 ----
#pragma unroll
    for (int x = 0; x < 2; x++) bfh[x] = rdfrag(pB, wc + 32 + x * 16 + ml);
    if (s1) { stB(t + 1, nxt, 2); stB(t + 1, nxt, 3); }
    __builtin_amdgcn_s_barrier();
    asm volatile("s_waitcnt lgkmcnt(0)");
    __builtin_amdgcn_s_setprio(1);
#pragma unroll
    for (int mt = 0; mt < 4; mt++)
#pragma unroll
      for (int nt = 0; nt < 2; nt++)
        acc[mt][2 + nt] = __builtin_amdgcn_mfma_scale_f32_16x16x128_f8f6f4(
            afl[mt], bfh[nt], acc[mt][2 + nt], 0, 0, 0, 0x7F7F7F7F, 0, 0x7F7F7F7F);
    __builtin_amdgcn_s_setprio(0);
    if (s1) asm volatile("s_waitcnt vmcnt(4)" ::: "memory");   // cur A1,A3 done; 4 B(t+1) in flight
    else    asm volatile("s_waitcnt vmcnt(0)" ::: "memory");   // last tile: only A1,A3 outstanding
    __builtin_amdgcn_s_barrier();

    // ---- ph2: (m-hi, n-hi); stage A(t+1) 0,2 ----
#pragma unroll
    for (int x = 0; x < 4; x++) afh[x] = rdfrag(pA, wr + 64 + x * 16 + ml);
    if (s1) { stA(t + 1, nxt, 0); stA(t + 1, nxt, 2); }
    __builtin_amdgcn_s_barrier();
    asm volatile("s_waitcnt lgkmcnt(0)");
    __builtin_amdgcn_s_setprio(1);
#pragma unroll
    for (int mt = 0; mt < 4; mt++)
#pragma unroll
      for (int nt = 0; nt < 2; nt++)
        acc[4 + mt][2 + nt] = __builtin_amdgcn_mfma_scale_f32_16x16x128_f8f6f4(
            afh[mt], bfh[nt], acc[4 + mt][2 + nt], 0, 0, 0, 0x7F7F7F7F, 0, 0x7F7F7F7F);
    __builtin_amdgcn_s_setprio(0);
    __builtin_amdgcn_s_barrier();

    // ---- ph3: (m-hi, n-lo), no ds_reads; stage A(t+1) 1,3; counted tile wait ----
    if (s1) { stA(t + 1, nxt, 1); stA(t + 1, nxt, 3); }
    __builtin_amdgcn_s_setprio(1);
#pragma unroll
    for (int mt = 0; mt < 4; mt++)
#pragma unroll
      for (int nt = 0; nt < 2; nt++)
        acc[4 + mt][nt] = __builtin_amdgcn_mfma_scale_f32_16x16x128_f8f6f4(
            afh[mt], bfl[nt], acc[4 + mt][nt], 0, 0, 0, 0x7F7F7F7F, 0, 0x7F7F7F7F);
    __builtin_amdgcn_s_setprio(0);
    if (s1) asm volatile("s_waitcnt vmcnt(2)" ::: "memory");   // leave A1,A3(t+1) in flight
    __builtin_amdgcn_s_barrier();
  }

  __hip_bfloat16* oc = C + (size_t)bz * HWP * SP;
  const int rq = (lane >> 4) * 4;
  const int cl = lane & 15;
#pragma unroll
  for (int mt = 0; mt < 8; mt++) {
    const int rb = m0 + wr + mt * 16 + rq;
#pragma unroll
    for (int nt = 0; nt < 4; nt++) {
      const int col = n0 + wc + nt * 16 + cl;
      if (col < SP) {
        f32x4 v = acc[mt][nt];
#pragma unroll
        for (int r = 0; r < 4; r++) {
          const int rr = rb + r;
          if (rr < HW) *reinterpret_cast<short*>(&oc[(size_t)rr * SP + col]) = f2bf(v[r]);
        }
      }
    }
  }
}

// ---------------- Row softmax: bf16 red -> bf16 attn (pad cols zeroed) ----------------
__global__ __launch_bounds__(256) void softmax_k(const __hip_bfloat16* __restrict__ red,
                                                 __hip_bfloat16* __restrict__ attn) {
  const int q = blockIdx.x;
  const int b = blockIdx.y;
  const __hip_bfloat16* row = red + ((size_t)b * HWP + q) * SP;
  __hip_bfloat16* orow = attn + ((size_t)b * HWP + q) * SP;
  const int tid = threadIdx.x;
  const int lane = tid & 63, wv = tid >> 6;
  const float SM = 20.0f / 1024.0f;   // undo 32*32 fp8 range scaling, apply temp

  float v0[8], v1[8];
  const int c1 = 256 + tid;           // second chunk id (valid when < 450)
  const bool has1 = (c1 < 450);

  float mx = -3.4e38f;
  {
    short8 pk = *reinterpret_cast<const short8*>(&row[(size_t)tid * 8]);
#pragma unroll
    for (int j = 0; j < 8; j++) { v0[j] = bf2f(pk[j]); mx = fmaxf(mx, v0[j]); }
  }
  if (has1) {
    short8 pk = *reinterpret_cast<const short8*>(&row[(size_t)c1 * 8]);
#pragma unroll
    for (int j = 0; j < 8; j++) { v1[j] = bf2f(pk[j]); mx = fmaxf(mx, v1[j]); }
  }
  for (int off = 32; off > 0; off >>= 1) mx = fmaxf(mx, __shfl_down(mx, off, 64));
  __shared__ float sm[4];
  if (lane == 0) sm[wv] = mx;
  __syncthreads();
  mx = fmaxf(fmaxf(sm[0], sm[1]), fmaxf(sm[2], sm[3]));

  float sum = 0.f;
#pragma unroll
  for (int j = 0; j < 8; j++) { float e = __expf((v0[j] - mx) * SM); v0[j] = e; sum += e; }
  if (has1) {
#pragma unroll
    for (int j = 0; j < 8; j++) { float e = __expf((v1[j] - mx) * SM); v1[j] = e; sum += e; }
  }
  for (int off = 32; off > 0; off >>= 1) sum += __shfl_down(sum, off, 64);
  __syncthreads();
  if (lane == 0) sm[wv] = sum;
  __syncthreads();
  const float inv = 1.f / (sm[0] + sm[1] + sm[2] + sm[3]);

  {
    short8 o;
#pragma unroll
    for (int j = 0; j < 8; j++) o[j] = f2bf(v0[j] * inv);
    *reinterpret_cast<short8*>(&orow[(size_t)tid * 8]) = o;
  }
  if (has1) {
    short8 o;
#pragma unroll
    for (int j = 0; j < 8; j++) o[j] = f2bf(v1[j] * inv);
    *reinterpret_cast<short8*>(&orow[(size_t)c1 * 8]) = o;
  } else if (c1 < 464) {            // pad chunks 450..463 -> zero (pv reads them)
    short8 z = {0, 0, 0, 0, 0, 0, 0, 0};
    *reinterpret_cast<short8*>(&orow[(size_t)c1 * 8]) = z;
  }
}

// ---------------- Cast f_s -> bf16 v, zero-pad s to SP ----------------
__global__ __launch_bounds__(256) void castv_k(const float* __restrict__ fs,
                                               __hip_bfloat16* __restrict__ vb) {
  const int idx = blockIdx.x * 256 + threadIdx.x;
  if (idx >= BD * CH * SP) return;
  const int s = idx % SP;
  const int bc = idx / SP;
  float v = (s < HW) ? fs[(size_t)bc * HW + s] : 0.f;
  *reinterpret_cast<short*>(&vb[idx]) = f2bf(v);
}

// ---------------- PV GEMM + blend epilogue, 128(c) x 64(q), BK=64, 2-phase dbuf ----
__global__ __launch_bounds__(256, 2) void pv_gemm(const __hip_bfloat16* __restrict__ A,
                                                  const __hip_bfloat16* __restrict__ B,
                                                  const float* __restrict__ fqin,
                                                  float* __restrict__ out) {
  const int bz = blockIdx.z;
  const int m0 = blockIdx.y * 128;   // c tile (2)
  const int n0 = blockIdx.x * 64;    // q tile (58)
  const int tid = threadIdx.x;
  const int lane = tid & 63;
  const int wv = tid >> 6;

  __shared__ uint8_t lA[2][128 * 128];   // 16 KB each: 128 c-rows x 128 B (BK=64 bf16)
  __shared__ uint8_t lB[2][64 * 128];    // 8 KB each   -> 48 KB total

  const uint8_t* gA = (const uint8_t*)(A + (size_t)bz * CH * SP);
  const uint8_t* gB = (const uint8_t*)(B + (size_t)bz * HWP * SP);

  const int r2 = tid >> 3;            // 0..31: row within a 32-row staging call
  const int slot = tid & 7;
  const int csw = (slot - r2) & 7;    // global 16B chunk this lane fetches
  const int wb16 = (tid & ~63) * 16;  // wave-uniform LDS byte base (1KB/wave/call)

  const int wr = (wv >> 1) * 64;      // m offset within tile
  const int wc = (wv & 1) * 32;       // n offset within tile
  const int ml = lane & 15;
  const int kg = lane >> 4;           // 16B chunk within 64B k-slice

  f32x4 acc[4][2];
#pragma unroll
  for (int i = 0; i < 4; i++)
#pragma unroll
    for (int jj = 0; jj < 2; jj++) acc[i][jj] = (f32x4){0.f, 0.f, 0.f, 0.f};

  auto stA = [&](int t, int bufi, int i) {
    load_lds16(gA + (size_t)(m0 + i * 32 + r2) * (SP * 2) + t * 128 + csw * 16,
               &lA[bufi][i * 4096 + wb16]);
  };
  auto stB = [&](int t, int bufi, int i) {
    load_lds16(gB + (size_t)(n0 + i * 32 + r2) * (SP * 2) + t * 128 + csw * 16,
               &lB[bufi][i * 4096 + wb16]);
  };

  auto rdf = [&](const uint8_t* base, int r, int s) -> short8 {
    return *reinterpret_cast<const short8*>(
        base + (r << 7) + (((s * 4 + kg) + r) & 7) * 16);
  };

  // prologue
  stA(0, 0, 0); stA(0, 0, 1); stA(0, 0, 2); stA(0, 0, 3);
  stB(0, 0, 0); stB(0, 0, 1);
  asm volatile("s_waitcnt vmcnt(0)" ::: "memory");
  __builtin_amdgcn_s_barrier();

  for (int t = 0; t < PVNT; t++) {
    const int cur = t & 1;
    const int nxt = cur ^ 1;
    const bool s1 = (t + 1 < PVNT);
    if (s1) {
      stA(t + 1, nxt, 0); stA(t + 1, nxt, 1); stA(t + 1, nxt, 2); stA(t + 1, nxt, 3);
      stB(t + 1, nxt, 0); stB(t + 1, nxt, 1);
    }
    const uint8_t* pA = lA[cur];
    const uint8_t* pB = lB[cur];
    short8 af[2][4], bq[2][2];
#pragma unroll
    for (int s = 0; s < 2; s++) {
#pragma unroll
      for (int mt = 0; mt < 4; mt++) af[s][mt] = rdf(pA, wr + mt * 16 + ml, s);
#pragma unroll
      for (int nt = 0; nt < 2; nt++) bq[s][nt] = rdf(pB, wc + nt * 16 + ml, s);
    }
    asm volatile("s_waitcnt lgkmcnt(0)");
#pragma unroll
    for (int s = 0; s < 2; s++)
#pragma unroll
      for (int mt = 0; mt < 4; mt++)
#pragma unroll
        for (int nt = 0; nt < 2; nt++)
          acc[mt][nt] = __builtin_amdgcn_mfma_f32_16x16x32_bf16(
              af[s][mt], bq[s][nt], acc[mt][nt], 0, 0, 0);
    if (s1) asm volatile("s_waitcnt vmcnt(0)" ::: "memory");
    __builtin_amdgcn_s_barrier();
  }

  const size_t obase = (size_t)bz * CH * HW;
  const size_t attoff = (size_t)BD * CH * HW;
  const int rq = (lane >> 4) * 4;
  const int cl = lane & 15;
#pragma unroll
  for (int mt = 0; mt < 4; mt++) {
    const int rb = m0 + wr + mt * 16 + rq;   // c
#pragma unroll
    for (int nt = 0; nt < 2; nt++) {
      const int col = n0 + wc + nt * 16 + cl;  // q
      if (col < HW) {
        f32x4 v = acc[mt][nt];
#pragma unroll
        for (int r = 0; r < 4; r++) {
          const int c = rb + r;
          size_t oi = obase + (size_t)c * HW + col;
          float att = v[r];
          out[oi] = (fqin[oi] + 0.3f * att) * (1.0f / 1.3f);
          out[attoff + oi] = att;
        }
      }
    }
  }
}

extern "C" void kernel_launch(void* const* d_in, const int* in_sizes, int n_in,
                              void* d_out, int out_size, void* d_ws, size_t ws_size,
                              hipStream_t stream) {
  const float* fqf = (const float*)d_in[0];   // [L,B,C,H,W]
  const float* fsf = (const float*)d_in[1];
  const float* f_q = (const float*)d_in[2];   // [B,CH,H,W]
  const float* f_s = (const float*)d_in[3];
  const float* cw  = (const float*)d_in[4];   // [L]
  float* out = (float*)d_out;

  char* w = (char*)d_ws;
  uint8_t* An = (uint8_t*)w;   w += (size_t)BD * HWP * KD;        // 45.6 MB
  uint8_t* Bn = (uint8_t*)w;   w += (size_t)BD * HWP * KD;        // 45.6 MB
  __hip_bfloat16* red = (__hip_bfloat16*)w;  w += (size_t)BD * HWP * SP * 2;  // 55.1 MB
  float* part = (float*)w;                                        // 1.5 MB
  __hip_bfloat16* attn = (__hip_bfloat16*)An;                     // 55.1 of 91.2 MB
  __hip_bfloat16* vb = (__hip_bfloat16*)(An + (size_t)BD * HWP * SP * 2);  // 3.8 MB
  (void)ws_size; (void)in_sizes; (void)n_in; (void)out_size;

  norm_k<<<dim3(15, NPLANE, 8), 256, 0, stream>>>(fqf, fsf, part);
  trans_k<<<dim3(57, NPLANE, 4), 256, 0, stream>>>(fqf, fsf, cw, part, An, Bn);
  gemm_main<<<dim3(450), 512, 0, stream>>>(An, Bn, red);
  softmax_k<<<dim3(HW, BD), 256, 0, stream>>>(red, attn);
  castv_k<<<(BD * CH * SP + 255) / 256, 256, 0, stream>>>(f_s, vb);
  pv_gemm<<<dim3(58, 2, BD), 256, 0, stream>>>(vb, attn, f_q, out);
}

// Round 6
// 733.138 us; speedup vs baseline: 1.0462x; 1.0462x over previous
//
#include <hip/hip_runtime.h>
#include <hip/hip_bf16.h>
#include <stdint.h>

// Problem constants
#define L3D 3
#define BD 2
#define CD 2048
#define HW 3600
#define CH 256
#define HWP 3712   // 29 * 128, padded hw
#define KD 6144    // L3D * CD  (bytes per row in fp8 An/Bn)
#define SP 3712    // padded support dim
#define SP2 3840   // partial-ssq q stride
#define LB6 6      // L3D*BD
#define NPLANE 12  // both inputs' (l,b) planes
#define NT 48      // K-tiles in main GEMM: KD / 128
#define PVNT 58    // K-steps in PV GEMM: SP / 64

typedef __attribute__((ext_vector_type(8))) short short8;
typedef __attribute__((ext_vector_type(4))) float f32x4;
typedef __attribute__((ext_vector_type(4))) int i32x4;
typedef __attribute__((ext_vector_type(8))) int i32x8;

__device__ __forceinline__ short f2bf(float v) {
  uint32_t x = __float_as_uint(v);
  uint32_t r = (x + 0x7FFFu + ((x >> 16) & 1u)) >> 16;   // RNE
  return (short)(r & 0xFFFFu);
}

__device__ __forceinline__ float bf2f(short s) {
  return __uint_as_float(((uint32_t)(uint16_t)s) << 16);
}

__device__ __forceinline__ void load_lds16(const void* g, void* l) {
  __builtin_amdgcn_global_load_lds(
      (const __attribute__((address_space(1))) void*)g,
      (__attribute__((address_space(3))) void*)l, 16, 0, 0);
}

// ---------------- norm_k: sum-of-squares partials ----------------
__global__ __launch_bounds__(256) void norm_k(const float* __restrict__ fq,
                                              const float* __restrict__ fs,
                                              float* __restrict__ part) {
  const int qt = blockIdx.x * 256;
  const int j = blockIdx.y;
  const int cs = blockIdx.z;
  const bool isq = (j < LB6);
  const int lb = isq ? j : j - LB6;
  const float* x = (isq ? fq : fs) + (size_t)lb * CD * HW;

  const int tid = threadIdx.x;
  const int qg = tid & 63;
  const int cp = tid >> 6;          // 0..3
  const int q4 = qt + qg * 4;

  f32x4 a0 = (f32x4){0.f, 0.f, 0.f, 0.f};
  f32x4 a1 = a0, a2 = a0, a3 = a0;
  if (q4 < HW) {                    // HW % 4 == 0: float4 fully valid or fully out
    const float* p = x + ((size_t)cs * 256 + cp) * HW + q4;
    for (int i = 0; i < 64; i += 4) {
      f32x4 v0 = *reinterpret_cast<const f32x4*>(p + (size_t)(i + 0) * 4 * HW);
      f32x4 v1 = *reinterpret_cast<const f32x4*>(p + (size_t)(i + 1) * 4 * HW);
      f32x4 v2 = *reinterpret_cast<const f32x4*>(p + (size_t)(i + 2) * 4 * HW);
      f32x4 v3 = *reinterpret_cast<const f32x4*>(p + (size_t)(i + 3) * 4 * HW);
      a0 += v0 * v0; a1 += v1 * v1; a2 += v2 * v2; a3 += v3 * v3;
    }
  }
  f32x4 a = (a0 + a1) + (a2 + a3);

  __shared__ float rb[4][256];
  *reinterpret_cast<f32x4*>(&rb[cp][qg * 4]) = a;
  __syncthreads();
  float s = rb[0][tid] + rb[1][tid] + rb[2][tid] + rb[3][tid];
  part[((size_t)cs * NPLANE + j) * SP2 + qt + tid] = s;
}

// ---------------- trans_k: normalize + transpose + fp8 pack ----------------
// float4 global loads (G13): lane = (tid&15)*4 q-offset, 16 c-rows per pass.
// LDS writes scalar into padded [64][65] tile (2-way bank aliasing = free).
__global__ __launch_bounds__(256) void trans_k(const float* __restrict__ fq,
                                               const float* __restrict__ fs,
                                               const float* __restrict__ cw,
                                               const float* __restrict__ part,
                                               uint8_t* __restrict__ An,
                                               uint8_t* __restrict__ Bn) {
  const int j = blockIdx.y;
  const int qt = blockIdx.x * 64;
  const int cg = blockIdx.z;
  const bool isq = (j < LB6);
  const int lb = isq ? j : j - LB6;
  const int l = lb / BD, b = lb % BD;
  const float* x = (isq ? fq : fs) + (size_t)lb * CD * HW;
  uint8_t* dst = isq ? An : Bn;

  const int tid = threadIdx.x;

  __shared__ float ivs[64];
  if (tid < 64) {
    const int q = qt + tid;
    float s = 0.f;
#pragma unroll
    for (int cs = 0; cs < 8; cs++) s += part[((size_t)cs * NPLANE + j) * SP2 + q];
    const float scale = isq ? (cw[l] * 32.0f) : 32.0f;  // fp8 range scaling
    ivs[tid] = (1.f / fmaxf(sqrtf(s), 1e-12f)) * scale;
  }

  __shared__ float tile[64][65];
  const int qv = (tid & 15) * 4;     // q offset within 64 (float4)
  const int r16 = tid >> 4;          // 0..15 c-row within pass
  const int q4 = qt + qv;
  const int wx = tid & 7, wy = tid >> 3;

  for (int t = 0; t < 8; t++) {
    const int ct = cg * 8 + t;
    const float* px = x + (size_t)ct * 64 * HW;
    __syncthreads();   // tile free (also covers ivs write on first iter)
#pragma unroll
    for (int p = 0; p < 4; p++) {
      const int cl = p * 16 + r16;
      f32x4 v = (f32x4){0.f, 0.f, 0.f, 0.f};
      if (q4 < HW)    // q4 % 4 == 0, HW % 4 == 0: never straddles the edge
        v = *reinterpret_cast<const f32x4*>(px + (size_t)cl * HW + q4);
      tile[cl][qv + 0] = v[0];
      tile[cl][qv + 1] = v[1];
      tile[cl][qv + 2] = v[2];
      tile[cl][qv + 3] = v[3];
    }
    __syncthreads();
#pragma unroll
    for (int it = 0; it < 2; it++) {
      int qrow = wy + it * 32;
      int qq = qt + qrow;
      if (qq < HW) {
        float iv = ivs[qrow];
        float v[8];
#pragma unroll
        for (int jj = 0; jj < 8; jj++) v[jj] = tile[wx * 8 + jj][qrow] * iv;
        int lo = 0, hi = 0;
        lo = __builtin_amdgcn_cvt_pk_fp8_f32(v[0], v[1], lo, false);
        lo = __builtin_amdgcn_cvt_pk_fp8_f32(v[2], v[3], lo, true);
        hi = __builtin_amdgcn_cvt_pk_fp8_f32(v[4], v[5], hi, false);
        hi = __builtin_amdgcn_cvt_pk_fp8_f32(v[6], v[7], hi, true);
        int2 pk = make_int2(lo, hi);
        *reinterpret_cast<int2*>(dst + ((size_t)b * HWP + qq) * KD +
                                 (size_t)l * CD + ct * 64 + wx * 8) = pk;
      }
    }
  }
}

// ---------------- Main GEMM: MX-fp8, 256x256 tile, BK=128, FAT 2-phase ----------------
// (R4 structure, measured fastest: 208 us / MfmaUtil 37.3%.)
// ONE barrier + ONE vmcnt(0) per K-tile. Per tile: read A-low + B frags; issue all
// 8 staging loads (t+1 -> nxt); MFMA cluster 1; read A-high; MFMA cluster 2;
// vmcnt(0) [issued ~2500cy earlier]; s_barrier. Waves drift within the tile so one
// wave's LDS reads overlap another's MFMAs.
// LDS layout: row = 128 B = 8 chunks of 16 B; chunk c of row r at slot (c+r)&7.
// Bijective XCD swizzle (450 blocks): m-major A-panel-sharing groups per XCD L2.
__global__ __launch_bounds__(512, 2) void gemm_main(const uint8_t* __restrict__ A,
                                                    const uint8_t* __restrict__ B,
                                                    __hip_bfloat16* __restrict__ C) {
  // --- bijective XCD swizzle: 450 = 8*56 + 2 -> chunks {57,57,56,56,56,56,56,56}
  const int orig = blockIdx.x;
  const int xcd = orig & 7, idx = orig >> 3;
  const int wg = (xcd < 2 ? xcd * 57 : 114 + (xcd - 2) * 56) + idx;
  const int bz = wg / 225;
  const int lin = wg % 225;
  const int m_t = lin / 15, n_t = lin % 15;   // m-major: 15 consecutive share A-panel
  const int m0 = m_t * 256, n0 = n_t * 256;
  const int tid = threadIdx.x;
  const int lane = tid & 63;
  const int wv = tid >> 6;               // 0..7 waves: 2 (m) x 4 (n)

  __shared__ uint8_t lA[2][256 * 128];   // 64 KB
  __shared__ uint8_t lB[2][256 * 128];   // 64 KB

  const uint8_t* gA = A + (size_t)bz * HWP * KD;
  const uint8_t* gB = B + (size_t)bz * HWP * KD;

  const int r_loc = tid >> 3;            // 0..63: row within a 64-row staging call
  const int slot = tid & 7;              // LDS slot within row
  const int csw = (slot - r_loc) & 7;    // global chunk this lane fetches
  const int wavebase = (tid & ~63) * 16; // wave-uniform LDS byte base

  const int wr = (wv >> 2) * 128;        // wave m offset: 0 / 128
  const int wc = (wv & 3) * 64;          // wave n offset: 0/64/128/192
  const int ml = lane & 15;
  const int kg = lane >> 4;              // k-group: 32 contiguous k bytes per lane

  f32x4 acc[8][4];
#pragma unroll
  for (int i = 0; i < 8; i++)
#pragma unroll
    for (int jj = 0; jj < 4; jj++) acc[i][jj] = (f32x4){0.f, 0.f, 0.f, 0.f};

  auto stA = [&](int t, int bufi, int i) {
    load_lds16(gA + (size_t)(m0 + i * 64 + r_loc) * KD + t * 128 + csw * 16,
               &lA[bufi][i * 8192 + wavebase]);
  };
  auto stB = [&](int t, int bufi, int i) {
    load_lds16(gB + (size_t)(n0 + i * 64 + r_loc) * KD + t * 128 + csw * 16,
               &lB[bufi][i * 8192 + wavebase]);
  };

  auto rdfrag = [&](const uint8_t* base, int row) -> i32x8 {
    const uint8_t* rp = base + (row << 7);
    i32x4 lo = *reinterpret_cast<const i32x4*>(rp + (((kg * 2)     + row) & 7) * 16);
    i32x4 hi = *reinterpret_cast<const i32x4*>(rp + (((kg * 2 + 1) + row) & 7) * 16);
    return __builtin_shufflevector(lo, hi, 0, 1, 2, 3, 4, 5, 6, 7);
  };

  // prologue: stage tile 0, drain, barrier
  stA(0, 0, 0); stA(0, 0, 1); stA(0, 0, 2); stA(0, 0, 3);
  stB(0, 0, 0); stB(0, 0, 1); stB(0, 0, 2); stB(0, 0, 3);
  asm volatile("s_waitcnt vmcnt(0)" ::: "memory");
  __builtin_amdgcn_s_barrier();

  for (int t = 0; t < NT; t++) {
    const int cur = t & 1;
    const int nxt = cur ^ 1;
    const uint8_t* pA = lA[cur];
    const uint8_t* pB = lB[cur];
    const bool s1 = (t + 1 < NT);
    i32x8 afl[4], afh[4], bfr[4];

    // reads for cluster 1: A m-low + B all
#pragma unroll
    for (int x = 0; x < 4; x++) afl[x] = rdfrag(pA, wr + x * 16 + ml);
#pragma unroll
    for (int x = 0; x < 4; x++) bfr[x] = rdfrag(pB, wc + x * 16 + ml);

    // stage tile t+1 fully (8 loads) -> in flight across both MFMA clusters
    if (s1) {
      stA(t + 1, nxt, 0); stA(t + 1, nxt, 1); stA(t + 1, nxt, 2); stA(t + 1, nxt, 3);
      stB(t + 1, nxt, 0); stB(t + 1, nxt, 1); stB(t + 1, nxt, 2); stB(t + 1, nxt, 3);
    }

    // MFMA cluster 1: m-low x n-all (compiler inserts partial lgkmcnt)
    __builtin_amdgcn_s_setprio(1);
#pragma unroll
    for (int mt = 0; mt < 4; mt++)
#pragma unroll
      for (int nt = 0; nt < 4; nt++)
        acc[mt][nt] = __builtin_amdgcn_mfma_scale_f32_16x16x128_f8f6f4(
            afl[mt], bfr[nt], acc[mt][nt], 0, 0, 0, 0x7F7F7F7F, 0, 0x7F7F7F7F);
    __builtin_amdgcn_s_setprio(0);

    // reads for cluster 2: A m-high
#pragma unroll
    for (int x = 0; x < 4; x++) afh[x] = rdfrag(pA, wr + 64 + x * 16 + ml);

    // MFMA cluster 2: m-high x n-all
    __builtin_amdgcn_s_setprio(1);
#pragma unroll
    for (int mt = 0; mt < 4; mt++)
#pragma unroll
      for (int nt = 0; nt < 4; nt++)
        acc[4 + mt][nt] = __builtin_amdgcn_mfma_scale_f32_16x16x128_f8f6f4(
            afh[mt], bfr[nt], acc[4 + mt][nt], 0, 0, 0, 0x7F7F7F7F, 0, 0x7F7F7F7F);
    __builtin_amdgcn_s_setprio(0);

    // staged loads were issued ~2500 cycles ago -> near-zero wait here
    if (s1) asm volatile("s_waitcnt vmcnt(0)" ::: "memory");
    __builtin_amdgcn_s_barrier();
  }

  __hip_bfloat16* oc = C + (size_t)bz * HWP * SP;
  const int rq = (lane >> 4) * 4;
  const int cl = lane & 15;
#pragma unroll
  for (int mt = 0; mt < 8; mt++) {
    const int rb = m0 + wr + mt * 16 + rq;
#pragma unroll
    for (int nt = 0; nt < 4; nt++) {
      const int col = n0 + wc + nt * 16 + cl;
      if (col < SP) {
        f32x4 v = acc[mt][nt];
#pragma unroll
        for (int r = 0; r < 4; r++) {
          const int rr = rb + r;
          if (rr < HW) *reinterpret_cast<short*>(&oc[(size_t)rr * SP + col]) = f2bf(v[r]);
        }
      }
    }
  }
}

// ---------------- Row softmax: bf16 red -> bf16 attn (pad cols zeroed) ----------------
__global__ __launch_bounds__(256) void softmax_k(const __hip_bfloat16* __restrict__ red,
                                                 __hip_bfloat16* __restrict__ attn) {
  const int q = blockIdx.x;
  const int b = blockIdx.y;
  const __hip_bfloat16* row = red + ((size_t)b * HWP + q) * SP;
  __hip_bfloat16* orow = attn + ((size_t)b * HWP + q) * SP;
  const int tid = threadIdx.x;
  const int lane = tid & 63, wv = tid >> 6;
  const float SM = 20.0f / 1024.0f;   // undo 32*32 fp8 range scaling, apply temp

  float v0[8], v1[8];
  const int c1 = 256 + tid;           // second chunk id (valid when < 450)
  const bool has1 = (c1 < 450);

  float mx = -3.4e38f;
  {
    short8 pk = *reinterpret_cast<const short8*>(&row[(size_t)tid * 8]);
#pragma unroll
    for (int j = 0; j < 8; j++) { v0[j] = bf2f(pk[j]); mx = fmaxf(mx, v0[j]); }
  }
  if (has1) {
    short8 pk = *reinterpret_cast<const short8*>(&row[(size_t)c1 * 8]);
#pragma unroll
    for (int j = 0; j < 8; j++) { v1[j] = bf2f(pk[j]); mx = fmaxf(mx, v1[j]); }
  }
  for (int off = 32; off > 0; off >>= 1) mx = fmaxf(mx, __shfl_down(mx, off, 64));
  __shared__ float sm[4];
  if (lane == 0) sm[wv] = mx;
  __syncthreads();
  mx = fmaxf(fmaxf(sm[0], sm[1]), fmaxf(sm[2], sm[3]));

  float sum = 0.f;
#pragma unroll
  for (int j = 0; j < 8; j++) { float e = __expf((v0[j] - mx) * SM); v0[j] = e; sum += e; }
  if (has1) {
#pragma unroll
    for (int j = 0; j < 8; j++) { float e = __expf((v1[j] - mx) * SM); v1[j] = e; sum += e; }
  }
  for (int off = 32; off > 0; off >>= 1) sum += __shfl_down(sum, off, 64);
  __syncthreads();
  if (lane == 0) sm[wv] = sum;
  __syncthreads();
  const float inv = 1.f / (sm[0] + sm[1] + sm[2] + sm[3]);

  {
    short8 o;
#pragma unroll
    for (int j = 0; j < 8; j++) o[j] = f2bf(v0[j] * inv);
    *reinterpret_cast<short8*>(&orow[(size_t)tid * 8]) = o;
  }
  if (has1) {
    short8 o;
#pragma unroll
    for (int j = 0; j < 8; j++) o[j] = f2bf(v1[j] * inv);
    *reinterpret_cast<short8*>(&orow[(size_t)c1 * 8]) = o;
  } else if (c1 < 464) {            // pad chunks 450..463 -> zero (pv reads them)
    short8 z = {0, 0, 0, 0, 0, 0, 0, 0};
    *reinterpret_cast<short8*>(&orow[(size_t)c1 * 8]) = z;
  }
}

// ---------------- Cast f_s -> bf16 v, zero-pad s to SP ----------------
__global__ __launch_bounds__(256) void castv_k(const float* __restrict__ fs,
                                               __hip_bfloat16* __restrict__ vb) {
  const int idx = blockIdx.x * 256 + threadIdx.x;
  if (idx >= BD * CH * SP) return;
  const int s = idx % SP;
  const int bc = idx / SP;
  float v = (s < HW) ? fs[(size_t)bc * HW + s] : 0.f;
  *reinterpret_cast<short*>(&vb[idx]) = f2bf(v);
}

// ---------------- PV GEMM + blend epilogue, 64(c) x 64(q), BK=64, 2-phase dbuf ----
// Smaller tiles: grid (58,4,2)=464 blocks (2x R5), 32 KB LDS + low VGPR ->
// multiple blocks/CU co-resident, so one block's MFMA hides another's staging
// latency (the old 232-block/48KB version was 1 block/CU and latency-bound).
// Same (chunk+row)&7 LDS swizzle; T3-min pipeline.
__global__ __launch_bounds__(256, 4) void pv_gemm(const __hip_bfloat16* __restrict__ A,
                                                  const __hip_bfloat16* __restrict__ B,
                                                  const float* __restrict__ fqin,
                                                  float* __restrict__ out) {
  const int bz = blockIdx.z;
  const int m0 = blockIdx.y * 64;    // c tile (4)
  const int n0 = blockIdx.x * 64;    // q tile (58)
  const int tid = threadIdx.x;
  const int lane = tid & 63;
  const int wv = tid >> 6;           // 0..3 waves: 2 (m) x 2 (n)

  __shared__ uint8_t lA[2][64 * 128];   // 8 KB each: 64 c-rows x 128 B (BK=64 bf16)
  __shared__ uint8_t lB[2][64 * 128];   // 8 KB each   -> 32 KB total

  const uint8_t* gA = (const uint8_t*)(A + (size_t)bz * CH * SP);
  const uint8_t* gB = (const uint8_t*)(B + (size_t)bz * HWP * SP);

  const int r2 = tid >> 3;            // 0..31: row within a 32-row staging call
  const int slot = tid & 7;
  const int csw = (slot - r2) & 7;    // global 16B chunk this lane fetches
  const int wb16 = (tid & ~63) * 16;  // wave-uniform LDS byte base (1KB/wave/call)

  const int wr = (wv >> 1) * 32;      // m offset within tile
  const int wc = (wv & 1) * 32;       // n offset within tile
  const int ml = lane & 15;
  const int kg = lane >> 4;           // 16B chunk within 64B k-slice

  f32x4 acc[2][2];
#pragma unroll
  for (int i = 0; i < 2; i++)
#pragma unroll
    for (int jj = 0; jj < 2; jj++) acc[i][jj] = (f32x4){0.f, 0.f, 0.f, 0.f};

  auto stA = [&](int t, int bufi, int i) {
    load_lds16(gA + (size_t)(m0 + i * 32 + r2) * (SP * 2) + t * 128 + csw * 16,
               &lA[bufi][i * 4096 + wb16]);
  };
  auto stB = [&](int t, int bufi, int i) {
    load_lds16(gB + (size_t)(n0 + i * 32 + r2) * (SP * 2) + t * 128 + csw * 16,
               &lB[bufi][i * 4096 + wb16]);
  };

  auto rdf = [&](const uint8_t* base, int r, int s) -> short8 {
    return *reinterpret_cast<const short8*>(
        base + (r << 7) + (((s * 4 + kg) + r) & 7) * 16);
  };

  // prologue
  stA(0, 0, 0); stA(0, 0, 1);
  stB(0, 0, 0); stB(0, 0, 1);
  asm volatile("s_waitcnt vmcnt(0)" ::: "memory");
  __builtin_amdgcn_s_barrier();

  for (int t = 0; t < PVNT; t++) {
    const int cur = t & 1;
    const int nxt = cur ^ 1;
    const bool s1 = (t + 1 < PVNT);
    if (s1) {
      stA(t + 1, nxt, 0); stA(t + 1, nxt, 1);
      stB(t + 1, nxt, 0); stB(t + 1, nxt, 1);
    }
    const uint8_t* pA = lA[cur];
    const uint8_t* pB = lB[cur];
    short8 af[2][2], bq[2][2];
#pragma unroll
    for (int s = 0; s < 2; s++) {
#pragma unroll
      for (int mt = 0; mt < 2; mt++) af[s][mt] = rdf(pA, wr + mt * 16 + ml, s);
#pragma unroll
      for (int nt = 0; nt < 2; nt++) bq[s][nt] = rdf(pB, wc + nt * 16 + ml, s);
    }
    asm volatile("s_waitcnt lgkmcnt(0)");
#pragma unroll
    for (int s = 0; s < 2; s++)
#pragma unroll
      for (int mt = 0; mt < 2; mt++)
#pragma unroll
        for (int nt = 0; nt < 2; nt++)
          acc[mt][nt] = __builtin_amdgcn_mfma_f32_16x16x32_bf16(
              af[s][mt], bq[s][nt], acc[mt][nt], 0, 0, 0);
    if (s1) asm volatile("s_waitcnt vmcnt(0)" ::: "memory");
    __builtin_amdgcn_s_barrier();
  }

  const size_t obase = (size_t)bz * CH * HW;
  const size_t attoff = (size_t)BD * CH * HW;
  const int rq = (lane >> 4) * 4;
  const int cl = lane & 15;
#pragma unroll
  for (int mt = 0; mt < 2; mt++) {
    const int rb = m0 + wr + mt * 16 + rq;   // c
#pragma unroll
    for (int nt = 0; nt < 2; nt++) {
      const int col = n0 + wc + nt * 16 + cl;  // q
      if (col < HW) {
        f32x4 v = acc[mt][nt];
#pragma unroll
        for (int r = 0; r < 4; r++) {
          const int c = rb + r;
          size_t oi = obase + (size_t)c * HW + col;
          float att = v[r];
          out[oi] = (fqin[oi] + 0.3f * att) * (1.0f / 1.3f);
          out[attoff + oi] = att;
        }
      }
    }
  }
}

extern "C" void kernel_launch(void* const* d_in, const int* in_sizes, int n_in,
                              void* d_out, int out_size, void* d_ws, size_t ws_size,
                              hipStream_t stream) {
  const float* fqf = (const float*)d_in[0];   // [L,B,C,H,W]
  const float* fsf = (const float*)d_in[1];
  const float* f_q = (const float*)d_in[2];   // [B,CH,H,W]
  const float* f_s = (const float*)d_in[3];
  const float* cw  = (const float*)d_in[4];   // [L]
  float* out = (float*)d_out;

  char* w = (char*)d_ws;
  uint8_t* An = (uint8_t*)w;   w += (size_t)BD * HWP * KD;        // 45.6 MB
  uint8_t* Bn = (uint8_t*)w;   w += (size_t)BD * HWP * KD;        // 45.6 MB
  __hip_bfloat16* red = (__hip_bfloat16*)w;  w += (size_t)BD * HWP * SP * 2;  // 55.1 MB
  float* part = (float*)w;                                        // 1.5 MB
  __hip_bfloat16* attn = (__hip_bfloat16*)An;                     // 55.1 of 91.2 MB
  __hip_bfloat16* vb = (__hip_bfloat16*)(An + (size_t)BD * HWP * SP * 2);  // 3.8 MB
  (void)ws_size; (void)in_sizes; (void)n_in; (void)out_size;

  norm_k<<<dim3(15, NPLANE, 8), 256, 0, stream>>>(fqf, fsf, part);
  trans_k<<<dim3(57, NPLANE, 4), 256, 0, stream>>>(fqf, fsf, cw, part, An, Bn);
  gemm_main<<<dim3(450), 512, 0, stream>>>(An, Bn, red);
  softmax_k<<<dim3(HW, BD), 256, 0, stream>>>(red, attn);
  castv_k<<<(BD * CH * SP + 255) / 256, 256, 0, stream>>>(f_s, vb);
  pv_gemm<<<dim3(58, 4, BD), 256, 0, stream>>>(vb, attn, f_q, out);
}